// Round 8
// baseline (57.144 us; speedup 1.0000x reference)
//
#include <hip/hip_runtime.h>
#include <hip/hip_bf16.h>

#define NN 512
#define FIN 128
#define HH 4
#define DD 64
#define SW 68   // permuted/padded e-width: 17 groups x 4
// lrelu(z) = 0.6*z + 0.4*|z|; a.lrelu folded: 0.6*(a.zi+a.zj) + sum_g sgn_g*|azi+azj|

// ws layout (floats):
//  h_ws   [8][512][64]  262144 @ 0
//  azi_ws [8][512][68]  278528 @ 262144   (|a|-scaled, e-permuted, zi+Wcb)
//  azjT   [8][68][512]  278528 @ 540672   (transposed: slot-major, j fastest)
//  adi_ws [8][512]      4096   @ 819200   (0.6 * sum_e a*zi')
//  adj_ws [8][512]      4096   @ 823296

// ---------------------------------------------------------------------------
// proj: unchanged from round 6 (validated). 512 blocks x 256.
// ---------------------------------------------------------------------------
__global__ __launch_bounds__(256) void proj_kernel(
    const float* __restrict__ x, const float* __restrict__ Wp,
    const float* __restrict__ bp, const float* __restrict__ Wc,
    const float* __restrict__ Wcb, const float* __restrict__ a,
    float* __restrict__ h_ws, float* __restrict__ azi_ws, float* __restrict__ azjT,
    float* __restrict__ adi_ws, float* __restrict__ adj_ws)
{
    int blk = blockIdx.x;
    int bh = blk >> 6;
    int n0 = (blk & 63) << 3;
    int b = bh >> 2, hh = bh & 3;

    __shared__ float xs[8 * FIN];
    __shared__ float hs[8][DD];
    __shared__ float Wcs[DD][2 * DD + 1];
    __shared__ float tzj[8][DD + 1];
    __shared__ int   slot2e[SW];
    __shared__ float slot2pa[SW];

    int t = threadIdx.x;

    ((float4*)xs)[t] = ((const float4*)(x + ((size_t)b * NN + n0) * FIN))[t];
    {
        const float4* wg = (const float4*)(Wc + (size_t)hh * DD * 2 * DD);
        #pragma unroll
        for (int k = 0; k < 8; ++k) {
            int idx = t + 256 * k;
            int r = idx >> 5, c4 = (idx & 31) * 4;
            float4 v = wg[idx];
            Wcs[r][c4] = v.x; Wcs[r][c4 + 1] = v.y;
            Wcs[r][c4 + 2] = v.z; Wcs[r][c4 + 3] = v.w;
        }
    }
    __syncthreads();

    int e = t & 63, w = t >> 6;            // rows w, w+4
    const float* Wph = Wp + (size_t)hh * FIN * DD;
    float bpv = bp[hh * DD + e];
    float acc0 = bpv, acc1 = bpv;
    #pragma unroll 8
    for (int i = 0; i < FIN; ++i) {
        float wv = Wph[i * DD + e];
        acc0 = fmaf(xs[w * FIN + i], wv, acc0);
        acc1 = fmaf(xs[(w + 4) * FIN + i], wv, acc1);
    }
    hs[w][e] = acc0; hs[w + 4][e] = acc1;
    float* hg = h_ws + ((size_t)bh * NN + n0) * DD;
    hg[w * DD + e] = acc0; hg[(w + 4) * DD + e] = acc1;
    __syncthreads();

    float zb = Wcb[hh * DD + e];
    float zi0 = zb, zi1 = zb, zj0 = 0.f, zj1 = 0.f;
    #pragma unroll 8
    for (int d2 = 0; d2 < DD; ++d2) {
        float w1 = Wcs[e][d2];
        float w2 = Wcs[e][DD + d2];
        float h0 = hs[w][d2], h1 = hs[w + 4][d2];
        zi0 = fmaf(h0, w1, zi0); zi1 = fmaf(h1, w1, zi1);
        zj0 = fmaf(h0, w2, zj0); zj1 = fmaf(h1, w2, zj1);
    }
    tzj[w][e] = zj0; tzj[w + 4][e] = zj1;

    float av = a[hh * DD + e];
    float p0 = av * zi0, p1 = av * zi1, q0 = av * zj0, q1 = av * zj1;
    #pragma unroll
    for (int off = 32; off; off >>= 1) {
        p0 += __shfl_xor(p0, off); p1 += __shfl_xor(p1, off);
        q0 += __shfl_xor(q0, off); q1 += __shfl_xor(q1, off);
    }
    if (e == 0) {
        adi_ws[bh * NN + n0 + w]     = 0.6f * p0;
        adi_ws[bh * NN + n0 + w + 4] = 0.6f * p1;
        adj_ws[bh * NN + n0 + w]     = 0.6f * q0;
        adj_ws[bh * NN + n0 + w + 4] = 0.6f * q1;
    }

    unsigned long long mask = __ballot(av >= 0.f);
    int np = __popcll(mask);
    int GP = (np + 3) >> 2;
    int below = __popcll(mask & ((1ull << e) - 1ull));
    int slot = (av >= 0.f) ? below : (4 * GP + (e - below));
    float pav = __builtin_fabsf(av);

    float* azib = azi_ws + ((size_t)bh * NN + n0) * SW;
    azib[w * SW + slot]       = pav * zi0;
    azib[(w + 4) * SW + slot] = pav * zi1;
    if (w == 0) { slot2e[slot] = e; slot2pa[slot] = pav; }
    int p1c = 4 * GP - np;
    if (e < 4) {
        int psl = (e < p1c) ? (np + e) : (4 * GP + 64 - np + (e - p1c));
        azib[w * SW + psl] = 0.f; azib[(w + 4) * SW + psl] = 0.f;
        if (w == 0) { slot2e[psl] = 0; slot2pa[psl] = 0.f; }
    }
    __syncthreads();

    for (int idx = t; idx < SW * 8; idx += 256) {
        int sl = idx >> 3, r = idx & 7;
        azjT[((size_t)bh * SW + sl) * NN + n0 + r] =
            slot2pa[sl] * tzj[r][slot2e[sl]];
    }
}

// ---------------------------------------------------------------------------
// attn_full: 8 i-rows per block, ALL 512 j with online softmax, direct out.
// grid = 8bh x 64it = 512 blocks x 256 thr. wave w owns rows 2w, 2w+1.
// ---------------------------------------------------------------------------
__global__ __launch_bounds__(256) void attn_full(
    const float* __restrict__ h_ws, const float* __restrict__ azi_ws,
    const float* __restrict__ azjT, const float* __restrict__ adi_ws,
    const float* __restrict__ adj_ws, const float* __restrict__ a,
    const float* __restrict__ bias_param, float* __restrict__ out)
{
    int blk = blockIdx.x;
    int bh = blk >> 6, it = blk & 63;
    int i0 = it << 3;
    int b = bh >> 2, hh = bh & 3;

    __shared__ float azis[8 * SW];     // 2.2 KB
    __shared__ float pbuf[8][64];      // 2 KB (wave-private rows)
    __shared__ float htile[64 * 64];   // 16 KB

    int t = threadIdx.x, lane = t & 63;
    int w = t >> 6;

    if (t < 136)
        ((float4*)azis)[t] =
            ((const float4*)(azi_ws + ((size_t)bh * NN + i0) * SW))[t];

    // group signs from ballot of a (lane = e)
    float av_e = a[hh * DD + lane];
    unsigned long long mask = __ballot(av_e >= 0.f);
    int GP = (__popcll(mask) + 3) >> 2;
    float sgn[17];
    #pragma unroll
    for (int k = 0; k < 17; ++k) sgn[k] = (k < GP) ? 0.4f : -0.4f;

    float adiA = adi_ws[bh * NN + i0 + 2 * w];
    float adiB = adi_ws[bh * NN + i0 + 2 * w + 1];

    float mrun0 = -1e30f, mrun1 = -1e30f;
    float srun0 = 0.f, srun1 = 0.f;
    float accA = 0.f, accB = 0.f;

    for (int jt = 0; jt < 8; ++jt) {
        __syncthreads();              // htile reuse guard (+ azis guard @ jt=0)
        {
            const float4* hsrc =
                (const float4*)(h_ws + ((size_t)bh * NN + jt * 64) * DD);
            float4* hdst = (float4*)htile;
            #pragma unroll
            for (int k = 0; k < 4; ++k) hdst[t + 256 * k] = hsrc[t + 256 * k];
        }
        // per-lane azj column (coalesced: 68 dword loads, stride 2 KB)
        float azjr[SW];
        {
            const float* ajT = azjT + (size_t)bh * SW * NN + jt * 64 + lane;
            #pragma unroll
            for (int k = 0; k < SW; ++k) azjr[k] = ajT[(size_t)k * NN];
        }
        float adjv = adj_ws[bh * NN + jt * 64 + lane];
        __syncthreads();              // htile ready

        float sc0, sc1;
        #pragma unroll
        for (int ii = 0; ii < 2; ++ii) {
            int i = 2 * w + ii;
            const float4* arow = (const float4*)(azis + i * SW);
            float c0 = 0.f, c1 = 0.f;
            #pragma unroll
            for (int k = 0; k < 17; ++k) {
                float4 zi4 = arow[k];             // uniform b128 broadcast
                float s = sgn[k];
                c0 = fmaf(s, __builtin_fabsf(zi4.x + azjr[4 * k + 0]), c0);
                c1 = fmaf(s, __builtin_fabsf(zi4.y + azjr[4 * k + 1]), c1);
                c0 = fmaf(s, __builtin_fabsf(zi4.z + azjr[4 * k + 2]), c0);
                c1 = fmaf(s, __builtin_fabsf(zi4.w + azjr[4 * k + 3]), c1);
            }
            float ev = ((ii == 0) ? adiA : adiB) + adjv + c0 + c1;
            float mt = ev;
            #pragma unroll
            for (int off = 32; off; off >>= 1) mt = fmaxf(mt, __shfl_xor(mt, off));
            float m_old = (ii == 0) ? mrun0 : mrun1;
            float m_new = fmaxf(m_old, mt);
            float sc = __expf(m_old - m_new);
            float p = __expf(ev - m_new);
            float psum = p;
            #pragma unroll
            for (int off = 32; off; off >>= 1) psum += __shfl_xor(psum, off);
            if (ii == 0) { srun0 = srun0 * sc + psum; mrun0 = m_new; sc0 = sc; }
            else         { srun1 = srun1 * sc + psum; mrun1 = m_new; sc1 = sc; }
            pbuf[i][lane] = p;
        }

        // PV for own rows (lane = d); pbuf rows are wave-private
        accA *= sc0; accB *= sc1;
        const float4* pA = (const float4*)pbuf[2 * w];
        const float4* pB = (const float4*)pbuf[2 * w + 1];
        #pragma unroll
        for (int k = 0; k < 16; ++k) {
            float4 a4 = pA[k], b4 = pB[k];
            float h0 = htile[(4 * k + 0) * 64 + lane];
            float h1 = htile[(4 * k + 1) * 64 + lane];
            float h2 = htile[(4 * k + 2) * 64 + lane];
            float h3 = htile[(4 * k + 3) * 64 + lane];
            accA = fmaf(a4.x, h0, accA); accB = fmaf(b4.x, h0, accB);
            accA = fmaf(a4.y, h1, accA); accB = fmaf(b4.y, h1, accB);
            accA = fmaf(a4.z, h2, accA); accB = fmaf(b4.z, h2, accB);
            accA = fmaf(a4.w, h3, accA); accB = fmaf(b4.w, h3, accB);
        }
    }

    float bpv = bias_param[hh * DD + lane];
    int iA = i0 + 2 * w, iB = iA + 1;
    out[((size_t)b * NN + iA) * (HH * DD) + hh * DD + lane] = accA / srun0 + bpv;
    out[((size_t)b * NN + iB) * (HH * DD) + hh * DD + lane] = accB / srun1 + bpv;
}

extern "C" void kernel_launch(void* const* d_in, const int* in_sizes, int n_in,
                              void* d_out, int out_size, void* d_ws, size_t ws_size,
                              hipStream_t stream) {
    const float* x    = (const float*)d_in[0];
    const float* Wp   = (const float*)d_in[1];
    const float* bp   = (const float*)d_in[2];
    const float* Wc   = (const float*)d_in[3];
    const float* Wcb  = (const float*)d_in[4];
    const float* a    = (const float*)d_in[5];
    const float* bpar = (const float*)d_in[6];
    float* out = (float*)d_out;

    float* ws     = (float*)d_ws;
    float* h_ws   = ws;
    float* azi_ws = ws + 262144;
    float* azjT   = ws + 540672;
    float* adi_ws = ws + 819200;
    float* adj_ws = ws + 823296;

    proj_kernel<<<dim3(512), dim3(256), 0, stream>>>(
        x, Wp, bp, Wc, Wcb, a, h_ws, azi_ws, azjT, adi_ws, adj_ws);
    attn_full<<<dim3(512), dim3(256), 0, stream>>>(
        h_ws, azi_ws, azjT, adi_ws, adj_ws, a, bpar, out);
}